// Round 1
// baseline (445.892 us; speedup 1.0000x reference)
//
#include <hip/hip_runtime.h>
#include <math.h>

// Problem constants (fixed by the reference).
#define BB    1024
#define SS    277
#define RR    76
#define ZZ    56
#define NLHS  24
#define NROWS (BB*SS)                       // 283648
#define ROWS_PER_BLOCK 16
#define FLOATS_PER_BLOCK (ROWS_PER_BLOCK*RR)   // 1216
#define VEC4_PER_BLOCK  (FLOATS_PER_BLOCK/4)   // 304
#define NBLOCKS (NROWS/ROWS_PER_BLOCK)         // 17728 (exact)
#define TOTAL_ELEMS 21558272.0                 // B*S*R

static_assert(NROWS % ROWS_PER_BLOCK == 0, "rows divide blocks");
static_assert(FLOATS_PER_BLOCK % 4 == 0, "float4 alignment");

__global__ void init_kernel(double* acc) {
    acc[0] = 0.0;   // BCE term sum
    acc[1] = 0.0;   // mom_err sum
}

// Masked-softmax BCE over rows of length R=76.
// One block = 16 rows; 4 waves x 4 rows each; lane covers r=lane and r=lane+64.
__global__ __launch_bounds__(256) void bce_kernel(
    const float* __restrict__ model,
    const float* __restrict__ target,
    const float* __restrict__ masks,
    const int*   __restrict__ ind_to_lhs,
    double* __restrict__ acc)
{
    __shared__ float sm_model[FLOATS_PER_BLOCK];
    __shared__ float sm_target[FLOATS_PER_BLOCK];
    __shared__ float sm_masks[NLHS*RR];   // 1824 floats
    __shared__ int   sm_lhs[RR];
    __shared__ float sm_wsum[4];

    const int tid = threadIdx.x;

    // Stage 16 rows of model & target via float4 (fully coalesced, 16B/lane).
    {
        const size_t base4 = (size_t)blockIdx.x * VEC4_PER_BLOCK;
        const float4* m4 = (const float4*)model;
        const float4* t4 = (const float4*)target;
        float4* smm4 = (float4*)sm_model;
        float4* smt4 = (float4*)sm_target;
        smm4[tid] = m4[base4 + tid];
        smt4[tid] = t4[base4 + tid];
        if (tid < VEC4_PER_BLOCK - 256) {           // remaining 48 vec4s
            smm4[256 + tid] = m4[base4 + 256 + tid];
            smt4[256 + tid] = t4[base4 + 256 + tid];
        }
    }
    // Stage masks + lhs map (tiny, L2-resident).
    for (int i = tid; i < NLHS*RR; i += 256) sm_masks[i] = masks[i];
    if (tid < RR) sm_lhs[tid] = ind_to_lhs[tid];
    __syncthreads();

    const int wave = tid >> 6;
    const int lane = tid & 63;
    float local_acc = 0.f;

    #pragma unroll
    for (int k = 0; k < 4; ++k) {
        const int row = wave*4 + k;
        const float* trow = sm_target + row*RR;
        const float* xrow = sm_model  + row*RR;

        const float t1 = trow[lane];
        const float t2 = (lane < RR-64) ? trow[64 + lane] : 0.f;

        // one-hot argmax via ballot (wave-uniform result)
        unsigned long long b1 = __ballot(t1 > 0.5f);
        int true_rule;
        if (b1) {
            true_rule = __builtin_ctzll(b1);
        } else {
            unsigned long long b2 = __ballot(t2 > 0.5f);
            true_rule = 64 + __builtin_ctzll(b2);
        }

        const int lhs = sm_lhs[true_rule];
        const float* mrow = sm_masks + lhs*RR;
        const float mk1 = mrow[lane];
        const float mk2 = (lane < RR-64) ? mrow[64 + lane] : 0.f;
        const float x1 = xrow[lane];
        const float x2 = (lane < RR-64) ? xrow[64 + lane] : 0.f;
        const bool u1 = (mk1 > 0.5f);
        const bool u2 = (lane < RR-64) && (mk2 > 0.5f);

        // softmax over unmasked entries only (see analysis: exact vs reference)
        float mx = fmaxf(u1 ? x1 : -INFINITY, u2 ? x2 : -INFINITY);
        #pragma unroll
        for (int off = 32; off; off >>= 1) mx = fmaxf(mx, __shfl_xor(mx, off, 64));

        float e = (u1 ? __expf(x1 - mx) : 0.f) + (u2 ? __expf(x2 - mx) : 0.f);
        #pragma unroll
        for (int off = 32; off; off >>= 1) e += __shfl_xor(e, off, 64);
        const float lse = mx + logf(e);

        // element r = lane
        {
            float term;
            if (u1) {
                const float lp = x1 - lse;
                const float p  = __expf(lp);
                term = (lane == true_rule) ? fmaxf(lp, -100.f)
                                           : fmaxf(log1pf(-p), -100.f);
            } else {
                term = (lane == true_rule) ? -100.f : 0.f;
            }
            local_acc += term;
        }
        // element r = lane + 64 (only lanes 0..11)
        if (lane < RR-64) {
            const int r = lane + 64;
            float term;
            if (u2) {
                const float lp = x2 - lse;
                const float p  = __expf(lp);
                term = (r == true_rule) ? fmaxf(lp, -100.f)
                                        : fmaxf(log1pf(-p), -100.f);
            } else {
                term = (r == true_rule) ? -100.f : 0.f;
            }
            local_acc += term;
        }
    }

    // wave reduce, then one double atomic per block
    #pragma unroll
    for (int off = 32; off; off >>= 1) local_acc += __shfl_xor(local_acc, off, 64);
    if (lane == 0) sm_wsum[wave] = local_acc;
    __syncthreads();
    if (tid == 0) {
        atomicAdd(acc, (double)(sm_wsum[0] + sm_wsum[1] + sm_wsum[2] + sm_wsum[3]));
    }
}

// mom_err: var = mu^T mu / B; var_err = var - I; sum(tanh(ve)*ve)/Z^2
//          + sum(avg_mu^2)/Z  (diagonal threads fold the avg_mu term in).
__global__ __launch_bounds__(256) void mom_kernel(
    const float* __restrict__ mu, double* __restrict__ mom_acc)
{
    const int tid = blockIdx.x * blockDim.x + threadIdx.x;
    float term = 0.f;
    if (tid < ZZ*ZZ) {
        const int i = tid / ZZ;
        const int j = tid % ZZ;
        float dot = 0.f, s1 = 0.f;
        for (int b = 0; b < BB; ++b) {
            const float a = mu[b*ZZ + i];
            const float c = mu[b*ZZ + j];
            dot = fmaf(a, c, dot);
            if (i == j) s1 += a;
        }
        const float v = dot * (1.f/BB) - ((i == j) ? 1.f : 0.f);
        term = tanhf(v) * v * (1.f/(ZZ*ZZ));
        if (i == j) {
            const float am = s1 * (1.f/BB);
            term += am * am * (1.f/ZZ);
        }
    }
    #pragma unroll
    for (int off = 32; off; off >>= 1) term += __shfl_xor(term, off, 64);
    if ((threadIdx.x & 63) == 0) atomicAdd(mom_acc, (double)term);
}

__global__ void final_kernel(const double* __restrict__ acc, float* __restrict__ out) {
    // bce = -sum/(B*S*R); BCE = S * bce; loss = BCE + mom_err
    const double loss = (double)SS * (-acc[0] / TOTAL_ELEMS) + acc[1];
    out[0] = (float)loss;
}

extern "C" void kernel_launch(void* const* d_in, const int* in_sizes, int n_in,
                              void* d_out, int out_size, void* d_ws, size_t ws_size,
                              hipStream_t stream) {
    const float* model  = (const float*)d_in[0];   // [B,S,R]
    const float* mu     = (const float*)d_in[1];   // [B,Z]
    // d_in[2] = log_var — unused by the reference output
    const float* target = (const float*)d_in[3];   // [B,S,R] one-hot
    const float* masks  = (const float*)d_in[4];   // [NLHS,R]
    const int*   ind    = (const int*)  d_in[5];   // [R]
    float* out = (float*)d_out;
    double* acc = (double*)d_ws;                   // acc[0]=bce sum, acc[1]=mom

    init_kernel<<<1, 1, 0, stream>>>(acc);
    bce_kernel<<<NBLOCKS, 256, 0, stream>>>(model, target, masks, ind, acc);
    mom_kernel<<<(ZZ*ZZ + 255)/256, 256, 0, stream>>>(mu, acc + 1);
    final_kernel<<<1, 1, 0, stream>>>(acc, out);
}

// Round 3
// 234.819 us; speedup vs baseline: 1.8989x; 1.8989x over previous
//
#include <hip/hip_runtime.h>
#include <math.h>

// Problem constants (fixed by the reference).
#define BB    1024
#define SS    277
#define RR    76
#define ZZ    56
#define NLHS  24
#define NROWS (BB*SS)                    // 283648
#define ROWS_PER_BLOCK 256
#define NBLOCKS (NROWS/ROWS_PER_BLOCK)   // 1108 (exact)
#define V4_PER_ROW (RR/4)                // 19
#define BLK_ELEMS (ROWS_PER_BLOCK*RR)    // 19456
#define TOTAL_ELEMS 21558272.0           // B*S*R

static_assert(NROWS % ROWS_PER_BLOCK == 0, "rows divide blocks");
static_assert(RR % 4 == 0, "rows are whole float4s");

#define LN2F  0.69314718056f
#define NLN2F (-144.26950409f)   /* -100 / ln2 */

// One thread = one full row of R=76 logits kept in registers.
// Per-block partial sum written to its own ws slot — NO global atomics.
__global__ __launch_bounds__(256) void bce_kernel(
    const float* __restrict__ model,
    const float* __restrict__ target,
    const float* __restrict__ masks,
    const int*   __restrict__ ind_to_lhs,
    double* __restrict__ partials)
{
    __shared__ unsigned int  smb[NLHS*4];       // 96-bit mask per lhs, padded to 4 words
    __shared__ unsigned char sm_idx[ROWS_PER_BLOCK];
    __shared__ int           sm_lhs[RR];
    __shared__ float         sm_red[4];

    const int tid = threadIdx.x;

    if (tid < NLHS*4) smb[tid] = 0u;
    sm_idx[tid] = 0;                    // defensive init (every row should get a hit)
    __syncthreads();

    // Pack masks into bitmasks (parallel, LDS atomicOr).
    for (int e = tid; e < NLHS*RR; e += 256) {
        const int lhs = e / RR;
        const int r   = e - lhs*RR;
        if (masks[e] > 0.5f)
            atomicOr(&smb[lhs*4 + (r >> 5)], 1u << (r & 31));
    }
    if (tid < RR) sm_lhs[tid] = ind_to_lhs[tid];

    const size_t blk_base = (size_t)blockIdx.x * BLK_ELEMS;

    // Coalesced scan of the one-hot target. A float4 never straddles rows
    // (76 = 19 float4s). One-hot => at most one hit per float4, exactly one
    // writer per row => race-free. WRITE AT EACH HIT (a thread can find hits
    // for multiple different rows across its 19 float4s — R2 bug).
    {
        const float4* t4 = (const float4*)(target + blk_base);
        #pragma unroll
        for (int k = 0; k < V4_PER_ROW; ++k) {
            const int v4 = tid + k*256;
            const float4 t = t4[v4];
            int he = -1;
            const int e = v4*4;
            if (t.x > 0.5f) he = e;
            if (t.y > 0.5f) he = e+1;
            if (t.z > 0.5f) he = e+2;
            if (t.w > 0.5f) he = e+3;
            if (he >= 0) {
                const int row = he / RR;
                sm_idx[row] = (unsigned char)(he - row*RR);
            }
        }
    }
    __syncthreads();

    // --- per-row compute, all from registers ---
    const int true_r = (int)sm_idx[tid];
    const int lhs    = sm_lhs[true_r];
    const unsigned int mw0 = smb[lhs*4 + 0];
    const unsigned int mw1 = smb[lhs*4 + 1];
    const unsigned int mw2 = smb[lhs*4 + 2];

    const float4* m4 = (const float4*)(model + blk_base + (size_t)tid * RR);
    float4 x[V4_PER_ROW];
    #pragma unroll
    for (int k = 0; k < V4_PER_ROW; ++k) x[k] = m4[k];   // 19 independent loads

    // Pass A: apply mask (-1e30 for masked), row max.
    float mx = -1e30f;
    #pragma unroll
    for (int k = 0; k < V4_PER_ROW; ++k) {
        #pragma unroll
        for (int c = 0; c < 4; ++c) {
            const int r = k*4 + c;
            const unsigned int mw = (r < 32) ? mw0 : ((r < 64) ? mw1 : mw2);
            float* xp = (&x[k].x) + c;
            const bool un = (mw >> (r & 31)) & 1u;
            const float xm = un ? *xp : -1e30f;
            *xp = xm;
            mx = fmaxf(mx, xm);
        }
    }

    // Pass B: e_r = exp(x_r - mx) (masked -> 0), sum.
    float s = 0.f;
    #pragma unroll
    for (int k = 0; k < V4_PER_ROW; ++k) {
        #pragma unroll
        for (int c = 0; c < 4; ++c) {
            float* xp = (&x[k].x) + c;
            const float e = __expf(*xp - mx);
            *xp = e;
            s += e;
        }
    }

    // Pass C: sum of clamped log(1-p) over ALL r (log2-domain, ln2 factored
    // out), plus p at the target index.
    const float inv = 1.f / s;
    float sum_l2 = 0.f;
    float p_true = 0.f;
    #pragma unroll
    for (int k = 0; k < V4_PER_ROW; ++k) {
        #pragma unroll
        for (int c = 0; c < 4; ++c) {
            const int r = k*4 + c;
            const float p  = (&x[k].x)[c] * inv;
            const float l2 = __log2f(1.f - p);
            sum_l2 += fmaxf(l2, NLN2F);
            if (r == true_r) p_true = p;
        }
    }
    float row_sum = LN2F * sum_l2;
    // Swap the true_r element's non-target term for the target term.
    const float l1c_t = fmaxf(LN2F * __log2f(1.f - p_true), -100.f);
    const float lp_t  = fmaxf(__logf(p_true), -100.f);   // p_true==0 (masked) -> -100
    row_sum += lp_t - l1c_t;

    // Block reduce -> one double partial per block (no atomics).
    #pragma unroll
    for (int off = 32; off; off >>= 1) row_sum += __shfl_xor(row_sum, off, 64);
    if ((tid & 63) == 0) sm_red[tid >> 6] = row_sum;
    __syncthreads();
    if (tid == 0)
        partials[blockIdx.x] = (double)((sm_red[0] + sm_red[1]) + (sm_red[2] + sm_red[3]));
}

// mom_err: block j computes var[:,j]; 4 waves split the batch.
__global__ __launch_bounds__(256) void mom_kernel(
    const float* __restrict__ mu, double* __restrict__ out)
{
    const int j    = blockIdx.x;          // 0..55
    const int w    = threadIdx.x >> 6;
    const int lane = threadIdx.x & 63;
    __shared__ float sdot[4][64];
    __shared__ float ssum[4];

    const int i  = (lane < ZZ) ? lane : 0;   // lanes >= ZZ masked out later
    float dot = 0.f, s1 = 0.f;
    const int b0 = 256*w;
    #pragma unroll 4
    for (int b = b0; b < b0 + 256; ++b) {
        const float c = mu[b*ZZ + j];     // wave-uniform broadcast
        const float a = mu[b*ZZ + i];     // coalesced across lanes
        dot = fmaf(a, c, dot);
        s1 += c;
    }
    sdot[w][lane] = dot;
    if (lane == 0) ssum[w] = s1;
    __syncthreads();

    if (w == 0) {
        float term = 0.f;
        if (lane < ZZ) {
            const float var = (sdot[0][lane] + sdot[1][lane] + sdot[2][lane] + sdot[3][lane]) * (1.f/BB);
            const float ve  = var - ((lane == j) ? 1.f : 0.f);
            term = tanhf(ve) * ve * (1.f/(ZZ*ZZ));
            if (lane == j) {
                const float am = (ssum[0] + ssum[1] + ssum[2] + ssum[3]) * (1.f/BB);
                term = fmaf(am*am, 1.f/ZZ, term);
            }
        }
        #pragma unroll
        for (int off = 32; off; off >>= 1) term += __shfl_xor(term, off, 64);
        if (lane == 0) out[j] = (double)term;
    }
}

// Sum 1108 bce partials + 56 mom partials with the right scales.
__global__ __launch_bounds__(256) void final_kernel(
    const double* __restrict__ partials, float* __restrict__ out)
{
    __shared__ double sred[4];
    const int tid = threadIdx.x;
    double s = 0.0;
    for (int k = tid; k < NBLOCKS; k += 256) s += partials[k];
    double m = (tid < ZZ) ? partials[NBLOCKS + tid] : 0.0;
    // loss = SS * (-s_total/TOTAL) + m_total, folded per-thread then reduced once
    double val = s * (-(double)SS / TOTAL_ELEMS) + m;
    #pragma unroll
    for (int off = 32; off; off >>= 1) val += __shfl_xor(val, off, 64);
    if ((tid & 63) == 0) sred[tid >> 6] = val;
    __syncthreads();
    if (tid == 0) out[0] = (float)((sred[0] + sred[1]) + (sred[2] + sred[3]));
}

extern "C" void kernel_launch(void* const* d_in, const int* in_sizes, int n_in,
                              void* d_out, int out_size, void* d_ws, size_t ws_size,
                              hipStream_t stream) {
    const float* model  = (const float*)d_in[0];   // [B,S,R]
    const float* mu     = (const float*)d_in[1];   // [B,Z]
    // d_in[2] = log_var — unused by the reference output
    const float* target = (const float*)d_in[3];   // [B,S,R] one-hot
    const float* masks  = (const float*)d_in[4];   // [NLHS,R]
    const int*   ind    = (const int*)  d_in[5];   // [R]
    float* out  = (float*)d_out;
    double* acc = (double*)d_ws;   // [0..1107] bce partials, [1108..1163] mom partials

    bce_kernel  <<<NBLOCKS, 256, 0, stream>>>(model, target, masks, ind, acc);
    mom_kernel  <<<ZZ,      256, 0, stream>>>(mu, acc + NBLOCKS);
    final_kernel<<<1,       256, 0, stream>>>(acc, out);
}

// Round 4
// 222.584 us; speedup vs baseline: 2.0033x; 1.0550x over previous
//
#include <hip/hip_runtime.h>
#include <math.h>

// Problem constants (fixed by the reference).
#define BB    1024
#define SS    277
#define RR    76
#define ZZ    56
#define NLHS  24
#define NROWS (BB*SS)                      // 283648
#define ROWS_PER_BLOCK 64
#define NBCE (NROWS/ROWS_PER_BLOCK)        // 4432 (exact)
#define NMOM ZZ                            // 56
#define NBLK (NBCE + NMOM)                 // 4488
#define V4_PER_BLOCK (ROWS_PER_BLOCK*RR/4) // 1216
#define BLK_ELEMS (ROWS_PER_BLOCK*RR)      // 4864
#define TOTAL_ELEMS 21558272.0             // B*S*R

static_assert(NROWS % ROWS_PER_BLOCK == 0, "rows divide blocks");

#define LN2F  0.69314718056f
#define NLN2F (-144.26950409f)   /* -100 / ln2 */

// blocks [0, NBCE): masked-softmax BCE, 64 rows/block, 4 threads per row.
// blocks [NBCE, NBLK): moment kernel, one column j per block.
// Per-block partials to distinct ws slots — no global atomics.
__global__ __launch_bounds__(256) void fused_kernel(
    const float* __restrict__ model,
    const float* __restrict__ target,
    const float* __restrict__ masks,
    const int*   __restrict__ ind_to_lhs,
    const float* __restrict__ mu,
    double* __restrict__ partials)
{
    __shared__ float         sm_x[BLK_ELEMS];     // 19456 B model tile
    __shared__ unsigned int  smb[NLHS*4];         // 96-bit mask per lhs
    __shared__ int           sm_lhs[RR];
    __shared__ unsigned char sm_idx[ROWS_PER_BLOCK];
    __shared__ float         sm_red[4];
    __shared__ float         sdot[4][64];
    __shared__ float         ssum[4];

    const int tid = threadIdx.x;

    if (blockIdx.x >= NBCE) {
        // ---------------- mom path: var[:,j] for j = blockIdx-NBCE ----------------
        const int j    = blockIdx.x - NBCE;
        const int w    = tid >> 6;
        const int lane = tid & 63;
        const int i    = (lane < ZZ) ? lane : 0;
        float dot = 0.f, s1 = 0.f;
        const int b0 = 256*w;
        #pragma unroll 4
        for (int b = b0; b < b0 + 256; ++b) {
            const float c = mu[b*ZZ + j];     // wave-uniform broadcast
            const float a = mu[b*ZZ + i];     // coalesced across lanes
            dot = fmaf(a, c, dot);
            s1 += c;
        }
        sdot[w][lane] = dot;
        if (lane == 0) ssum[w] = s1;
        __syncthreads();
        if (w == 0) {
            float term = 0.f;
            if (lane < ZZ) {
                const float var = (sdot[0][lane]+sdot[1][lane]+sdot[2][lane]+sdot[3][lane]) * (1.f/BB);
                const float ve  = var - ((lane == j) ? 1.f : 0.f);
                term = tanhf(ve) * ve * (1.f/(ZZ*ZZ));
                if (lane == j) {
                    const float am = (ssum[0]+ssum[1]+ssum[2]+ssum[3]) * (1.f/BB);
                    term = fmaf(am*am, 1.f/ZZ, term);
                }
            }
            #pragma unroll
            for (int off = 32; off; off >>= 1) term += __shfl_xor(term, off, 64);
            if (lane == 0) partials[blockIdx.x] = (double)term;
        }
        return;
    }

    // ---------------- bce path ----------------
    if (tid < NLHS*4) smb[tid] = 0u;
    if (tid < ROWS_PER_BLOCK) sm_idx[tid] = 0;
    __syncthreads();

    // Pack masks into bitmasks (parallel, LDS atomicOr).
    for (int e = tid; e < NLHS*RR; e += 256) {
        const int lhs = e / RR;
        const int r   = e - lhs*RR;
        if (masks[e] > 0.5f)
            atomicOr(&smb[lhs*4 + (r >> 5)], 1u << (r & 31));
    }
    if (tid < RR) sm_lhs[tid] = ind_to_lhs[tid];

    const size_t blk_base = (size_t)blockIdx.x * BLK_ELEMS;   // 19456 B, 16B-aligned

    // Stage model tile -> LDS, fully coalesced float4.
    {
        const float4* m4  = (const float4*)(model + blk_base);
        float4*       sx4 = (float4*)sm_x;
        #pragma unroll
        for (int k = 0; k < 4; ++k) sx4[tid + 256*k] = m4[tid + 256*k];
        if (tid < V4_PER_BLOCK - 1024) sx4[1024 + tid] = m4[1024 + tid];
    }

    // Coalesced one-hot scan; write sm_idx AT EACH HIT (one writer per row).
    {
        const float4* t4 = (const float4*)(target + blk_base);
        #pragma unroll
        for (int k = 0; k < 5; ++k) {
            const int v4 = tid + 256*k;
            if (v4 < V4_PER_BLOCK) {
                const float4 t = t4[v4];
                int he = -1;
                const int e = v4*4;
                if (t.x > 0.5f) he = e;
                if (t.y > 0.5f) he = e+1;
                if (t.z > 0.5f) he = e+2;
                if (t.w > 0.5f) he = e+3;
                if (he >= 0) {
                    const int row = he / RR;
                    sm_idx[row] = (unsigned char)(he - row*RR);
                }
            }
        }
    }
    __syncthreads();

    // Quad-cooperative row compute: row = tid>>2, sub-lane t = tid&3 handles
    // chunks c = t+4k (c<19). Invalid chunk (t==3,k==4) treated as fully masked.
    const int row    = tid >> 2;
    const int t      = tid & 3;
    const int true_r = (int)sm_idx[row];
    const int lhs    = sm_lhs[true_r];
    const unsigned int w0 = smb[lhs*4 + 0];
    const unsigned int w1 = smb[lhs*4 + 1];
    const unsigned int w2 = smb[lhs*4 + 2];

    const float4* xr = (const float4*)(sm_x + row*RR);
    float4 v[5];

    // Pass A: load + mask (-1e30) + thread-local max.
    float mx = -1e30f;
    #pragma unroll
    for (int k = 0; k < 5; ++k) {
        const int c = t + 4*k;
        float4 xv = (c < 19) ? xr[c] : make_float4(-1e30f,-1e30f,-1e30f,-1e30f);
        #pragma unroll
        for (int cc = 0; cc < 4; ++cc) {
            const int r = c*4 + cc;
            const unsigned int mw = (r < 32) ? w0 : ((r < 64) ? w1 : w2);
            float* xp = (&xv.x) + cc;
            const bool un = (r < RR) && ((mw >> (r & 31)) & 1u);
            const float xm = un ? *xp : -1e30f;
            *xp = xm;
            mx = fmaxf(mx, xm);
        }
        v[k] = xv;
    }
    // quad max
    mx = fmaxf(mx, __shfl_xor(mx, 1, 64));
    mx = fmaxf(mx, __shfl_xor(mx, 2, 64));

    // Pass B: e = exp(x-mx) (masked -> 0), quad sum.
    float s = 0.f;
    #pragma unroll
    for (int k = 0; k < 5; ++k) {
        #pragma unroll
        for (int cc = 0; cc < 4; ++cc) {
            float* xp = (&v[k].x) + cc;
            const float e = __expf(*xp - mx);
            *xp = e;
            s += e;
        }
    }
    s += __shfl_xor(s, 1, 64);
    s += __shfl_xor(s, 2, 64);
    const float inv = 1.f / s;

    // Pass C: clamped log(1-p) over all elements (log2-domain), grab p_true.
    float sum_l2 = 0.f;
    float p_true = 0.f;
    bool  owner  = false;
    #pragma unroll
    for (int k = 0; k < 5; ++k) {
        const int c = t + 4*k;
        #pragma unroll
        for (int cc = 0; cc < 4; ++cc) {
            const int r = c*4 + cc;
            const float p  = (&v[k].x)[cc] * inv;
            const float l2 = __log2f(1.f - p);
            sum_l2 += fmaxf(l2, NLN2F);
            if (r == true_r) { p_true = p; owner = true; }
        }
    }
    float row_sum = LN2F * sum_l2;
    if (owner) {
        const float l1c_t = fmaxf(LN2F * __log2f(1.f - p_true), -100.f);
        const float lp_t  = fmaxf(__logf(p_true), -100.f);  // p_true==0 (masked) -> -100
        row_sum += lp_t - l1c_t;
    }

    // Wave butterfly (sums 16 rows incl. quad partials), then block combine.
    #pragma unroll
    for (int off = 32; off; off >>= 1) row_sum += __shfl_xor(row_sum, off, 64);
    if ((tid & 63) == 0) sm_red[tid >> 6] = row_sum;
    __syncthreads();
    if (tid == 0)
        partials[blockIdx.x] = (double)((sm_red[0] + sm_red[1]) + (sm_red[2] + sm_red[3]));
}

// Sum NBCE bce partials + NMOM mom partials with the right scales.
__global__ __launch_bounds__(256) void final_kernel(
    const double* __restrict__ partials, float* __restrict__ out)
{
    __shared__ double sred[4];
    const int tid = threadIdx.x;
    double s = 0.0;
    for (int k = tid; k < NBCE; k += 256) s += partials[k];
    double m = (tid < NMOM) ? partials[NBCE + tid] : 0.0;
    double val = s * (-(double)SS / TOTAL_ELEMS) + m;
    #pragma unroll
    for (int off = 32; off; off >>= 1) val += __shfl_xor(val, off, 64);
    if ((tid & 63) == 0) sred[tid >> 6] = val;
    __syncthreads();
    if (tid == 0) out[0] = (float)((sred[0] + sred[1]) + (sred[2] + sred[3]));
}

extern "C" void kernel_launch(void* const* d_in, const int* in_sizes, int n_in,
                              void* d_out, int out_size, void* d_ws, size_t ws_size,
                              hipStream_t stream) {
    const float* model  = (const float*)d_in[0];   // [B,S,R]
    const float* mu     = (const float*)d_in[1];   // [B,Z]
    // d_in[2] = log_var — unused by the reference output
    const float* target = (const float*)d_in[3];   // [B,S,R] one-hot
    const float* masks  = (const float*)d_in[4];   // [NLHS,R]
    const int*   ind    = (const int*)  d_in[5];   // [R]
    float* out  = (float*)d_out;
    double* acc = (double*)d_ws;   // [0..NBCE) bce partials, [NBCE..NBLK) mom partials

    fused_kernel<<<NBLK, 256, 0, stream>>>(model, target, masks, ind, mu, acc);
    final_kernel<<<1,    256, 0, stream>>>(acc, out);
}

// Round 5
// 218.476 us; speedup vs baseline: 2.0409x; 1.0188x over previous
//
#include <hip/hip_runtime.h>
#include <math.h>

// Problem constants (fixed by the reference).
#define BB    1024
#define SS    277
#define RR    76
#define ZZ    56
#define NLHS  24
#define NROWS (BB*SS)                      // 283648
#define ROWS_PER_TILE 64
#define TT    4                            // tiles per block (double-buffered)
#define TILE_ELEMS (ROWS_PER_TILE*RR)      // 4864
#define NBCE (NROWS/(ROWS_PER_TILE*TT))    // 1108 (exact)
#define NMOM ZZ                            // 56
#define NBLK (NBCE + NMOM)                 // 1164
#define TOTAL_ELEMS 21558272.0             // B*S*R

static_assert(NROWS % (ROWS_PER_TILE*TT) == 0, "rows divide blocks");

#define LN2F  0.69314718056f
#define NLN2F (-144.26950409f)   /* -100 / ln2 */

// blocks [0, NBCE): masked-softmax BCE. 4 tiles x 64 rows, quad-per-row,
//   all data loaded straight to registers (quad layout is ~coalesced:
//   16x64B segments per wave-instruction). No LDS data staging, no barriers
//   in the tile loop. Per-block partial -> distinct ws slot (no atomics).
// blocks [NBCE, NBLK): moment kernel, one column j per block.
__global__ __launch_bounds__(256) void fused_kernel(
    const float* __restrict__ model,
    const float* __restrict__ target,
    const float* __restrict__ masks,
    const int*   __restrict__ ind_to_lhs,
    const float* __restrict__ mu,
    double* __restrict__ partials)
{
    __shared__ uint4 smb[NLHS];        // 96-bit mask per lhs (in .x/.y/.z)
    __shared__ int   sm_lhs[RR];
    __shared__ float sm_red[4];
    __shared__ float sdot[4][64];      // mom path only
    __shared__ float ssum[4];

    const int tid = threadIdx.x;

    if (blockIdx.x >= NBCE) {
        // ---------------- mom path: var[:,j] for j = blockIdx-NBCE -------------
        const int j    = blockIdx.x - NBCE;
        const int w    = tid >> 6;
        const int lane = tid & 63;
        const int i    = (lane < ZZ) ? lane : 0;
        float dot = 0.f, s1 = 0.f;
        const int b0 = 256*w;
        #pragma unroll 4
        for (int b = b0; b < b0 + 256; ++b) {
            const float c = mu[b*ZZ + j];     // wave-uniform broadcast
            const float a = mu[b*ZZ + i];     // coalesced across lanes
            dot = fmaf(a, c, dot);
            s1 += c;
        }
        sdot[w][lane] = dot;
        if (lane == 0) ssum[w] = s1;
        __syncthreads();
        if (w == 0) {
            float term = 0.f;
            if (lane < ZZ) {
                const float var = (sdot[0][lane]+sdot[1][lane]+sdot[2][lane]+sdot[3][lane]) * (1.f/BB);
                const float ve  = var - ((lane == j) ? 1.f : 0.f);
                term = tanhf(ve) * ve * (1.f/(ZZ*ZZ));
                if (lane == j) {
                    const float am = (ssum[0]+ssum[1]+ssum[2]+ssum[3]) * (1.f/BB);
                    term = fmaf(am*am, 1.f/ZZ, term);
                }
            }
            #pragma unroll
            for (int off = 32; off; off >>= 1) term += __shfl_xor(term, off, 64);
            if (lane == 0) partials[blockIdx.x] = (double)term;
        }
        return;
    }

    // ---------------- bce path ----------------
    // One-time mask setup (tiny; L2-resident inputs).
    if (tid < NLHS*4) ((unsigned int*)smb)[tid] = 0u;
    __syncthreads();
    for (int e = tid; e < NLHS*RR; e += 256) {
        const int lhs = e / RR;
        const int r   = e - lhs*RR;
        if (masks[e] > 0.5f)
            atomicOr(&((unsigned int*)smb)[lhs*4 + (r >> 5)], 1u << (r & 31));
    }
    if (tid < RR) sm_lhs[tid] = ind_to_lhs[tid];
    __syncthreads();

    const int rloc = tid >> 2;   // row within tile: 0..63
    const int t    = tid & 3;    // quad sub-lane: chunks c = t+4k, c<19

    const size_t blk_elem0 = (size_t)blockIdx.x * (TT*TILE_ELEMS) + (size_t)rloc*RR;

    float acc_thread = 0.f;

    float4 v[5], tv[5];
    // Load tile 0 (10 independent dwordx4 loads).
    {
        const float4* mr = (const float4*)(model  + blk_elem0);
        const float4* tr = (const float4*)(target + blk_elem0);
        #pragma unroll
        for (int k = 0; k < 5; ++k) {
            const int c = t + 4*k;
            v[k]  = (c < 19) ? mr[c] : make_float4(-1e30f,-1e30f,-1e30f,-1e30f);
            tv[k] = (c < 19) ? tr[c] : make_float4(0.f,0.f,0.f,0.f);
        }
    }

    #pragma unroll
    for (int tt = 0; tt < TT; ++tt) {
        // Prefetch next tile while computing this one.
        float4 vn[5], tvn[5];
        if (tt + 1 < TT) {
            const size_t nb = blk_elem0 + (size_t)(tt+1)*TILE_ELEMS;
            const float4* mr = (const float4*)(model  + nb);
            const float4* tr = (const float4*)(target + nb);
            #pragma unroll
            for (int k = 0; k < 5; ++k) {
                const int c = t + 4*k;
                vn[k]  = (c < 19) ? mr[c] : make_float4(-1e30f,-1e30f,-1e30f,-1e30f);
                tvn[k] = (c < 19) ? tr[c] : make_float4(0.f,0.f,0.f,0.f);
            }
        }

        // One-hot index from this thread's own target chunks, quad-combined.
        int he = -1;
        #pragma unroll
        for (int k = 0; k < 5; ++k) {
            const int c = t + 4*k;
            const int e = c*4;
            if (tv[k].x > 0.5f) he = e;
            if (tv[k].y > 0.5f) he = e+1;
            if (tv[k].z > 0.5f) he = e+2;
            if (tv[k].w > 0.5f) he = e+3;
        }
        he = max(he, __shfl_xor(he, 1, 64));
        he = max(he, __shfl_xor(he, 2, 64));
        const int true_r = he;                  // exactly one hit per row

        const int lhs = sm_lhs[true_r];
        const uint4 mb = smb[lhs];
        const unsigned int w0 = mb.x, w1 = mb.y, w2 = mb.z;

        // Pass A: mask (-1e30) + quad max.
        float mx = -1e30f;
        #pragma unroll
        for (int k = 0; k < 5; ++k) {
            #pragma unroll
            for (int cc = 0; cc < 4; ++cc) {
                const int r = (t + 4*k)*4 + cc;
                const unsigned int mw = (r < 32) ? w0 : ((r < 64) ? w1 : w2);
                float* xp = (&v[k].x) + cc;
                const bool un = (r < RR) && ((mw >> (r & 31)) & 1u);
                const float xm = un ? *xp : -1e30f;
                *xp = xm;
                mx = fmaxf(mx, xm);
            }
        }
        mx = fmaxf(mx, __shfl_xor(mx, 1, 64));
        mx = fmaxf(mx, __shfl_xor(mx, 2, 64));

        // Pass B: e = exp(x-mx) (masked -> 0), quad sum.
        float s = 0.f;
        #pragma unroll
        for (int k = 0; k < 5; ++k) {
            #pragma unroll
            for (int cc = 0; cc < 4; ++cc) {
                float* xp = (&v[k].x) + cc;
                const float e = __expf(*xp - mx);
                *xp = e;
                s += e;
            }
        }
        s += __shfl_xor(s, 1, 64);
        s += __shfl_xor(s, 2, 64);
        const float inv = 1.f / s;

        // Pass C: clamped log(1-p) (log2-domain), owner swaps in target term.
        float sum_l2 = 0.f;
        float p_true = 0.f;
        bool  owner  = false;
        #pragma unroll
        for (int k = 0; k < 5; ++k) {
            #pragma unroll
            for (int cc = 0; cc < 4; ++cc) {
                const int r = (t + 4*k)*4 + cc;
                const float p  = (&v[k].x)[cc] * inv;
                const float l2 = __log2f(1.f - p);
                sum_l2 += fmaxf(l2, NLN2F);
                if (r == true_r) { p_true = p; owner = true; }
            }
        }
        float part = LN2F * sum_l2;
        if (owner) {
            const float l1c_t = fmaxf(LN2F * __log2f(1.f - p_true), -100.f);
            const float lp_t  = fmaxf(__logf(p_true), -100.f);   // masked target -> -100
            part += lp_t - l1c_t;
        }
        acc_thread += part;

        // rotate buffers
        #pragma unroll
        for (int k = 0; k < 5; ++k) { v[k] = vn[k]; tv[k] = tvn[k]; }
    }

    // One butterfly per block (amortized over 4 tiles), then block combine.
    #pragma unroll
    for (int off = 32; off; off >>= 1) acc_thread += __shfl_xor(acc_thread, off, 64);
    if ((tid & 63) == 0) sm_red[tid >> 6] = acc_thread;
    __syncthreads();
    if (tid == 0)
        partials[blockIdx.x] = (double)((sm_red[0] + sm_red[1]) + (sm_red[2] + sm_red[3]));
}

// Sum NBCE bce partials + NMOM mom partials with the right scales.
__global__ __launch_bounds__(256) void final_kernel(
    const double* __restrict__ partials, float* __restrict__ out)
{
    __shared__ double sred[4];
    const int tid = threadIdx.x;
    double s = 0.0;
    for (int k = tid; k < NBCE; k += 256) s += partials[k];
    double m = (tid < NMOM) ? partials[NBCE + tid] : 0.0;
    double val = s * (-(double)SS / TOTAL_ELEMS) + m;
    #pragma unroll
    for (int off = 32; off; off >>= 1) val += __shfl_xor(val, off, 64);
    if ((tid & 63) == 0) sred[tid >> 6] = val;
    __syncthreads();
    if (tid == 0) out[0] = (float)((sred[0] + sred[1]) + (sred[2] + sred[3]));
}

extern "C" void kernel_launch(void* const* d_in, const int* in_sizes, int n_in,
                              void* d_out, int out_size, void* d_ws, size_t ws_size,
                              hipStream_t stream) {
    const float* model  = (const float*)d_in[0];   // [B,S,R]
    const float* mu     = (const float*)d_in[1];   // [B,Z]
    // d_in[2] = log_var — unused by the reference output
    const float* target = (const float*)d_in[3];   // [B,S,R] one-hot
    const float* masks  = (const float*)d_in[4];   // [NLHS,R]
    const int*   ind    = (const int*)  d_in[5];   // [R]
    float* out  = (float*)d_out;
    double* acc = (double*)d_ws;   // [0..NBCE) bce partials, [NBCE..NBLK) mom partials

    fused_kernel<<<NBLK, 256, 0, stream>>>(model, target, masks, ind, mu, acc);
    final_kernel<<<1,    256, 0, stream>>>(acc, out);
}